// Round 6
// baseline (12959.428 us; speedup 1.0000x reference)
//
#include <hip/hip_runtime.h>

#define D 256
#define L_TOT 13294

__device__ __forceinline__ float bf2f(unsigned short u) {
    return __uint_as_float(((unsigned int)u) << 16);
}
__device__ __forceinline__ unsigned short f2bf(float f) {
    unsigned int u = __float_as_uint(f);
    u += 0x7FFFu + ((u >> 16) & 1u);   // round-to-nearest-even
    return (unsigned short)(u >> 16);
}

// ---------------------------------------------------------------------------
// Dtype probe on level_embed: bf16 data -> ~100% sane exponents; fp32 read as
// halfwords -> ~60%. flag=1 means bf16 inputs.
// ---------------------------------------------------------------------------
__global__ void probe_k(const unsigned short* __restrict__ u, int n, int* __restrict__ flag)
{
    __shared__ int cnt;
    if (threadIdx.x == 0) cnt = 0;
    __syncthreads();
    int c = 0;
    for (int i = threadIdx.x; i < n; i += 256) {
        const int e = (u[i] >> 7) & 0xFF;
        if (e == 0 || (e >= 96 && e <= 150)) ++c;
    }
    atomicAdd(&cnt, c);
    __syncthreads();
    if (threadIdx.x == 0) *flag = (cnt * 10 > n * 9) ? 1 : 0;
}

__global__ __launch_bounds__(256) void convert_k(
    const void* __restrict__ src, unsigned short* __restrict__ dst, int n,
    const int* __restrict__ flag)
{
    const int i = blockIdx.x * 256 + threadIdx.x;
    if (i >= n) return;
    if (*flag) dst[i] = ((const unsigned short*)src)[i];
    else       dst[i] = f2bf(((const float*)src)[i]);
}

// ---------------------------------------------------------------------------
// Flatten (B,D,H,W) src inputs -> state bf16 (tok,D).
// ---------------------------------------------------------------------------
__global__ __launch_bounds__(256) void flatten_k(
    const void* __restrict__ s0, const void* __restrict__ s1,
    const void* __restrict__ s2, const void* __restrict__ s3,
    const int* __restrict__ flag, unsigned short* __restrict__ state)
{
    const long e = (long)blockIdx.x * 256 + threadIdx.x;
    const int d = (int)(e & 255);
    const long tok = e >> 8;
    const int b = (int)(tok / L_TOT);
    const int t = (int)(tok - (long)b * L_TOT);
    const void *sp;
    int hw, idx;
    if (t < 10000)      { sp = s0; hw = 10000; idx = t;          }
    else if (t < 12500) { sp = s1; hw = 2500;  idx = t - 10000;  }
    else if (t < 13125) { sp = s2; hw = 625;   idx = t - 12500;  }
    else                { sp = s3; hw = 169;   idx = t - 13125;  }
    const long a = ((long)b * D + d) * hw + idx;
    state[e] = (*flag) ? ((const unsigned short*)sp)[a]
                       : f2bf(((const float*)sp)[a]);
}

// Per-layer pos recompute: pos = pos_input + level_embed (bf16 out).
__global__ __launch_bounds__(256) void posflat_k(
    const void* __restrict__ p0, const void* __restrict__ p1,
    const void* __restrict__ p2, const void* __restrict__ p3,
    const unsigned short* __restrict__ lev, const int* __restrict__ flag,
    unsigned short* __restrict__ pos)
{
    const long e = (long)blockIdx.x * 256 + threadIdx.x;
    const int d = (int)(e & 255);
    const long tok = e >> 8;
    const int b = (int)(tok / L_TOT);
    const int t = (int)(tok - (long)b * L_TOT);
    const void *pp;
    int hw, idx, l;
    if (t < 10000)      { pp = p0; hw = 10000; idx = t;          l = 0; }
    else if (t < 12500) { pp = p1; hw = 2500;  idx = t - 10000;  l = 1; }
    else if (t < 13125) { pp = p2; hw = 625;   idx = t - 12500;  l = 2; }
    else                { pp = p3; hw = 169;   idx = t - 13125;  l = 3; }
    const long a = ((long)b * D + d) * hw + idx;
    const float pv = (*flag) ? bf2f(((const unsigned short*)pp)[a])
                             : ((const float*)pp)[a];
    pos[e] = f2bf(pv + bf2f(lev[l * D + d]));
}

// ---------------------------------------------------------------------------
// K=256 GEMM: out[tok,0:N] = x(+pos)@W + bias (+resid). bf16 io, fp32 acc.
// ---------------------------------------------------------------------------
template<int N, bool ADDPOS, bool RESID>
__global__ __launch_bounds__(256) void gemm_k(
    const unsigned short* __restrict__ x,
    const unsigned short* __restrict__ pos,
    const unsigned short* __restrict__ Wt,
    const unsigned short* __restrict__ bias,
    const unsigned short* __restrict__ resid,
    unsigned short* __restrict__ outp, long nt)
{
    constexpr int COLG = N / 4;
    constexpr int TG = 256 / COLG;
    constexpr int TPT = 16 / TG;
    __shared__ float xs[16][D];
    const int tid = threadIdx.x;
    const long tok_base = (long)blockIdx.x * 16;
#pragma unroll
    for (int i = 0; i < 16; ++i) {
        const long tok = tok_base + i;
        float v = 0.f;
        if (tok < nt) {
            const long e = tok * D + tid;
            v = bf2f(x[e]);
            if (ADDPOS) v += bf2f(pos[e]);
        }
        xs[i][tid] = v;
    }
    __syncthreads();
    const int cg = tid % COLG, tg = tid / COLG;
    const int c0 = cg * 4, t0 = tg * TPT;
    float acc[TPT][4];
    {
        const float b0 = bf2f(bias[c0 + 0]), b1 = bf2f(bias[c0 + 1]);
        const float b2 = bf2f(bias[c0 + 2]), b3 = bf2f(bias[c0 + 3]);
#pragma unroll
        for (int tt = 0; tt < TPT; ++tt) {
            acc[tt][0] = b0; acc[tt][1] = b1; acc[tt][2] = b2; acc[tt][3] = b3;
        }
    }
    for (int k0 = 0; k0 < D; k0 += 4) {
        float xv[TPT][4];
#pragma unroll
        for (int tt = 0; tt < TPT; ++tt)
            *(float4*)(&xv[tt][0]) = *(const float4*)(&xs[t0 + tt][k0]);
#pragma unroll
        for (int j = 0; j < 4; ++j) {
            const unsigned long long wq =
                *(const unsigned long long*)(&Wt[(long)(k0 + j) * N + c0]);
            const float w0 = bf2f((unsigned short)(wq));
            const float w1 = bf2f((unsigned short)(wq >> 16));
            const float w2 = bf2f((unsigned short)(wq >> 32));
            const float w3 = bf2f((unsigned short)(wq >> 48));
#pragma unroll
            for (int tt = 0; tt < TPT; ++tt) {
                const float xk = xv[tt][j];
                acc[tt][0] = fmaf(xk, w0, acc[tt][0]);
                acc[tt][1] = fmaf(xk, w1, acc[tt][1]);
                acc[tt][2] = fmaf(xk, w2, acc[tt][2]);
                acc[tt][3] = fmaf(xk, w3, acc[tt][3]);
            }
        }
    }
#pragma unroll
    for (int tt = 0; tt < TPT; ++tt) {
        const long tok = tok_base + t0 + tt;
        if (tok >= nt) continue;
        const long e = tok * N + c0;
#pragma unroll
        for (int j = 0; j < 4; ++j) {
            float v = acc[tt][j];
            if (RESID) v += bf2f(resid[tok * D + c0 + j]);
            outp[e + j] = f2bf(v);
        }
    }
}

// ---------------------------------------------------------------------------
// Deformable sampling: one block per token; thread = (head, channel).
// attn output may alias the pos buffer (pos dead by now).
// ---------------------------------------------------------------------------
__global__ __launch_bounds__(256) void sample_k(
    const unsigned short* __restrict__ off, const unsigned short* __restrict__ aw,
    const unsigned short* __restrict__ val, unsigned short* __restrict__ attn)
{
    __shared__ float offs[256];
    __shared__ float awv[128];
    __shared__ float hinv[8];
    __shared__ int   cidx[128][4];
    __shared__ float cw[128][4];
    const long tok = blockIdx.x;
    const int tid = threadIdx.x;
    const int b = (int)(tok / L_TOT);
    const int t = (int)(tok - (long)b * L_TOT);
    offs[tid] = bf2f(off[tok * 256 + tid]);
    if (tid < 128) awv[tid] = bf2f(aw[tok * 128 + tid]);
    __syncthreads();
    if (tid < 8) {
        float m = -1e30f;
        for (int j = 0; j < 16; ++j) m = fmaxf(m, awv[tid * 16 + j]);
        float s = 0.f;
        for (int j = 0; j < 16; ++j) {
            const float e = expf(awv[tid * 16 + j] - m);
            awv[tid * 16 + j] = e; s += e;
        }
        hinv[tid] = 1.f / s;
    }
    __syncthreads();
    int st0, W0;
    if (t < 10000)      { st0 = 0;     W0 = 100; }
    else if (t < 12500) { st0 = 10000; W0 = 50;  }
    else if (t < 13125) { st0 = 12500; W0 = 25;  }
    else                { st0 = 13125; W0 = 13;  }
    const int i0 = t - st0;
    const int yy = i0 / W0;
    const int xx = i0 - yy * W0;
    const float gx = (xx + 0.5f) / (float)W0;
    const float gy = (yy + 0.5f) / (float)W0;   // square levels
    if (tid < 128) {
        const int u = tid;
        const int l = (u >> 2) & 3;
        const int Wv  = (l == 0) ? 100 : (l == 1) ? 50 : (l == 2) ? 25 : 13;
        const int stl = (l == 0) ? 0 : (l == 1) ? 10000 : (l == 2) ? 12500 : 13125;
        const float ox = offs[2 * u], oy = offs[2 * u + 1];
        const float px = (gx + ox / (float)Wv) * Wv - 0.5f;
        const float py = (gy + oy / (float)Wv) * Wv - 0.5f;
        const float fx = floorf(px), fy = floorf(py);
        const float wx1 = px - fx, wy1 = py - fy;
        const int x0 = (int)fx, y0 = (int)fy;
        const float a = awv[u] * hinv[u >> 4];
#pragma unroll
        for (int c = 0; c < 4; ++c) {
            const int xi = x0 + (c & 1);
            const int yi = y0 + (c >> 1);
            const float wgt = ((c & 1) ? wx1 : 1.f - wx1) * ((c >> 1) ? wy1 : 1.f - wy1);
            const bool ok = (xi >= 0) && (xi < Wv) && (yi >= 0) && (yi < Wv);
            cidx[u][c] = ok ? (stl + yi * Wv + xi) : 0;
            cw[u][c]   = ok ? wgt * a : 0.f;
        }
    }
    __syncthreads();
    const int h = tid >> 5, dch = tid & 31;
    const unsigned short* vb = val + ((long)b * L_TOT) * 256 + h * 32 + dch;
    float o = 0.f;
    for (int lp = 0; lp < 16; ++lp) {
        const int u = h * 16 + lp;
#pragma unroll
        for (int c = 0; c < 4; ++c) {
            const float w = cw[u][c];
            if (w != 0.f)
                o = fmaf(w, bf2f(vb[(long)cidx[u][c] * 256]), o);
        }
    }
    __syncthreads();   // all LDS consumers done before attn overwrites pos
    attn[tok * 256 + tid] = f2bf(o);
}

// ---------------------------------------------------------------------------
// LayerNorm over D=256. Block = 4 waves = 4 tokens; lane = 4 channels.
// ---------------------------------------------------------------------------
__global__ __launch_bounds__(256) void ln_k(
    const unsigned short* __restrict__ y,
    const unsigned short* __restrict__ g, const unsigned short* __restrict__ bb,
    unsigned short* __restrict__ out, long nt)
{
    const int wv = threadIdx.x >> 6;
    const int lane = threadIdx.x & 63;
    const long tok = (long)blockIdx.x * 4 + wv;
    if (tok >= nt) return;
    const ushort4 v4 = *(const ushort4*)(y + tok * D + lane * 4);
    const float v0 = bf2f(v4.x), v1 = bf2f(v4.y), v2 = bf2f(v4.z), v3 = bf2f(v4.w);
    float s = v0 + v1 + v2 + v3;
#pragma unroll
    for (int m = 1; m < 64; m <<= 1) s += __shfl_xor(s, m);
    const float mean = s * (1.f / D);
    const float d0 = v0 - mean, d1 = v1 - mean, d2 = v2 - mean, d3 = v3 - mean;
    float q = d0 * d0 + d1 * d1 + d2 * d2 + d3 * d3;
#pragma unroll
    for (int m = 1; m < 64; m <<= 1) q += __shfl_xor(q, m);
    const float rstd = rsqrtf(q * (1.f / D) + 1e-5f);
    const int c0 = lane * 4;
    ushort4 o;
    o.x = f2bf(d0 * rstd * bf2f(g[c0 + 0]) + bf2f(bb[c0 + 0]));
    o.y = f2bf(d1 * rstd * bf2f(g[c0 + 1]) + bf2f(bb[c0 + 1]));
    o.z = f2bf(d2 * rstd * bf2f(g[c0 + 2]) + bf2f(bb[c0 + 2]));
    o.w = f2bf(d3 * rstd * bf2f(g[c0 + 3]) + bf2f(bb[c0 + 3]));
    *(ushort4*)(out + tok * D + lane * 4) = o;
}

// ---------------------------------------------------------------------------
// Fused FFN: y = x + relu(x@f1+b1)@f2 + b2, dff in 64-wide chunks via LDS.
// ---------------------------------------------------------------------------
__global__ __launch_bounds__(256) void ffn_k(
    const unsigned short* __restrict__ x,
    const unsigned short* __restrict__ w1, const unsigned short* __restrict__ b1,
    const unsigned short* __restrict__ w2, const unsigned short* __restrict__ b2,
    unsigned short* __restrict__ outy, long nt, int dff)
{
    __shared__ float xs[16][D];
    __shared__ float hs[64][16];
    const int tid = threadIdx.x;
    const long tok_base = (long)blockIdx.x * 16;
#pragma unroll
    for (int i = 0; i < 16; ++i) {
        const long tok = tok_base + i;
        xs[i][tid] = (tok < nt) ? bf2f(x[tok * D + tid]) : 0.f;
    }
    const int c = tid;
    float acc[16];
    {
        const float b2v = bf2f(b2[c]);
#pragma unroll
        for (int t = 0; t < 16; ++t) acc[t] = b2v;
    }
    const int fl = tid & 63, tg = tid >> 6, t0 = tg * 4;
    __syncthreads();
    for (int ff0 = 0; ff0 < dff; ff0 += 64) {
        const int f = ff0 + fl;
        float h[4];
        { const float b1v = bf2f(b1[f]); h[0] = h[1] = h[2] = h[3] = b1v; }
        for (int k0 = 0; k0 < D; k0 += 4) {
            float xr[4][4];
#pragma unroll
            for (int tt = 0; tt < 4; ++tt)
                *(float4*)(&xr[tt][0]) = *(const float4*)(&xs[t0 + tt][k0]);
#pragma unroll
            for (int j = 0; j < 4; ++j) {
                const float wv = bf2f(w1[(long)(k0 + j) * dff + f]);
#pragma unroll
                for (int tt = 0; tt < 4; ++tt) h[tt] = fmaf(xr[tt][j], wv, h[tt]);
            }
        }
#pragma unroll
        for (int tt = 0; tt < 4; ++tt) h[tt] = fmaxf(h[tt], 0.f);
        *(float4*)(&hs[fl][t0]) = *(const float4*)(&h[0]);
        __syncthreads();
        for (int fi = 0; fi < 64; ++fi) {
            const float wv = bf2f(w2[(long)(ff0 + fi) * D + c]);
            const float4* hr = (const float4*)(&hs[fi][0]);
            const float4 h0 = hr[0], h1 = hr[1], h2 = hr[2], h3 = hr[3];
            acc[0]  = fmaf(h0.x, wv, acc[0]);  acc[1]  = fmaf(h0.y, wv, acc[1]);
            acc[2]  = fmaf(h0.z, wv, acc[2]);  acc[3]  = fmaf(h0.w, wv, acc[3]);
            acc[4]  = fmaf(h1.x, wv, acc[4]);  acc[5]  = fmaf(h1.y, wv, acc[5]);
            acc[6]  = fmaf(h1.z, wv, acc[6]);  acc[7]  = fmaf(h1.w, wv, acc[7]);
            acc[8]  = fmaf(h2.x, wv, acc[8]);  acc[9]  = fmaf(h2.y, wv, acc[9]);
            acc[10] = fmaf(h2.z, wv, acc[10]); acc[11] = fmaf(h2.w, wv, acc[11]);
            acc[12] = fmaf(h3.x, wv, acc[12]); acc[13] = fmaf(h3.y, wv, acc[13]);
            acc[14] = fmaf(h3.z, wv, acc[14]); acc[15] = fmaf(h3.w, wv, acc[15]);
        }
        __syncthreads();
    }
#pragma unroll
    for (int t = 0; t < 16; ++t) {
        const long tok = tok_base + t;
        if (tok < nt) outy[tok * D + c] = f2bf(acc[t] + xs[t][c]);
    }
}

// ---------------------------------------------------------------------------
// Finalize: OUTPUT IS FP32. d_out[0, osz-4) = final src (bf16 state -> f32);
// d_out[osz-4, osz) = level_start_index as f32.
// ---------------------------------------------------------------------------
__global__ __launch_bounds__(256) void finalize_k(
    const unsigned short* __restrict__ state, float* __restrict__ out, long osz)
{
    const long e = (long)blockIdx.x * 256 + threadIdx.x;
    const long n0 = osz - 4;
    if (e < n0) out[e] = bf2f(state[e]);
    if (e < 4) {
        const float st[4] = {0.f, 10000.f, 12500.f, 13125.f};
        out[n0 + e] = st[e];
    }
}

extern "C" void kernel_launch(void* const* d_in, const int* in_sizes, int n_in,
                              void* d_out, int out_size, void* d_ws, size_t ws_size,
                              hipStream_t stream)
{
    (void)n_in; (void)ws_size;
    const long osz = (long)out_size;
    const long nt = (osz - 4) / D;                      // total tokens
    const int nlayers = in_sizes[9] / (D * D);          // so_w: (NL, 256, 256)
    const int dff = in_sizes[19] / (nlayers * D);       // f1_w: (NL, 256, DFF)

    char* ws = (char*)d_ws;
    int* flag = (int*)ws;  ws += 256;
    unsigned short* wc = (unsigned short*)ws;           // canonical bf16 weights
    long off[25]; long acc_off = 0;
    for (int i = 8; i <= 24; ++i) { off[i] = acc_off; acc_off += in_sizes[i]; }
    ws += ((acc_off * 2 + 255) / 256) * 256;
    const size_t SZ_BF = (size_t)nt * D * 2;
    unsigned short* state     = (unsigned short*)ws;  ws += SZ_BF;  // running src (bf16)
    unsigned short* val_b     = (unsigned short*)ws;  ws += SZ_BF;
    unsigned short* offy_b    = (unsigned short*)ws;  ws += SZ_BF;  // offsets, then pre-LN y
    unsigned short* posattn_b = (unsigned short*)ws;  ws += SZ_BF;  // pos, then attn
    unsigned short* aw_b      = (unsigned short*)ws;  ws += (size_t)nt * 128 * 2;
    // total ~131.5 MB @ B=4 (round-4-proven size)

    probe_k<<<1, 256, 0, stream>>>((const unsigned short*)d_in[8], in_sizes[8], flag);

    for (int i = 8; i <= 24; ++i)
        convert_k<<<(in_sizes[i] + 255) / 256, 256, 0, stream>>>(
            d_in[i], wc + off[i], in_sizes[i], flag);

    flatten_k<<<(int)nt, 256, 0, stream>>>(
        d_in[0], d_in[2], d_in[4], d_in[6], flag, state);

    const int GB = (int)((nt + 15) / 16);
    const int LB = (int)((nt + 3) / 4);

    for (int i = 0; i < nlayers; ++i) {
        posflat_k<<<(int)nt, 256, 0, stream>>>(                // pos (into posattn_b)
            d_in[1], d_in[3], d_in[5], d_in[7], wc + off[8], flag, posattn_b);
        gemm_k<256, false, false><<<GB, 256, 0, stream>>>(     // value
            state, nullptr, wc + off[13] + (long)i * D * D, wc + off[14] + i * D,
            nullptr, val_b, nt);
        gemm_k<256, true, false><<<GB, 256, 0, stream>>>(      // sampling offsets
            state, posattn_b, wc + off[9] + (long)i * D * 256, wc + off[10] + i * 256,
            nullptr, offy_b, nt);
        gemm_k<128, true, false><<<GB, 256, 0, stream>>>(      // attn logits
            state, posattn_b, wc + off[11] + (long)i * D * 128, wc + off[12] + i * 128,
            nullptr, aw_b, nt);
        sample_k<<<(int)nt, 256, 0, stream>>>(offy_b, aw_b, val_b, posattn_b);
        gemm_k<256, false, true><<<GB, 256, 0, stream>>>(      // out-proj + resid
            posattn_b, nullptr, wc + off[15] + (long)i * D * D, wc + off[16] + i * D,
            state, offy_b, nt);
        ln_k<<<LB, 256, 0, stream>>>(offy_b, wc + off[17] + i * D, wc + off[18] + i * D,
                                     state, nt);
        ffn_k<<<GB, 256, 0, stream>>>(
            state, wc + off[19] + (long)i * D * dff, wc + off[20] + i * dff,
            wc + off[21] + (long)i * dff * D, wc + off[22] + i * D, offy_b, nt, dff);
        ln_k<<<LB, 256, 0, stream>>>(offy_b, wc + off[23] + i * D, wc + off[24] + i * D,
                                     state, nt);
    }

    finalize_k<<<(int)((osz - 4 + 255) / 256), 256, 0, stream>>>(
        state, (float*)d_out, osz);
}